// Round 2
// baseline (485.105 us; speedup 1.0000x reference)
//
#include <hip/hip_runtime.h>

#define BATCH 256
#define SEQ_T 512
#define CIN   6
#define RES   256

// One workgroup (1024 threads = 16 waves) per batch row; loops over all T.
// Phase 1: wave w -> k-chunk kk = w>>1 (8 groups x 32 k). Thread handles
//   outputs {2r, 2r+1}, r = tid&127. W slice (32 x float2) pinned in VGPRs
//   via asm. h chunk is wave-uniform: 1 ds_read_b32 + 32 v_readlane -> SGPRs,
//   inner loop is pure v_fmac_f32 with SGPR broadcast operand (no LDS).
// Phase 2 (tid<256): reduce 8 partials + x@W_in + tanh, write h and out.
__global__ __launch_bounds__(1024, 4)
void esn_scan_kernel(const float* __restrict__ x,
                     const float* __restrict__ W_in,
                     const float* __restrict__ W_res,
                     float* __restrict__ out) {
    __shared__ float h[2][RES];
    __shared__ float part[8][RES];

    const int tid = threadIdx.x;
    const int b   = blockIdx.x;
    const int r   = tid & 127;       // output pair index: cols {2r, 2r+1}
    const int kk  = tid >> 7;        // k-group 0..7, chunk [32kk, 32kk+32)

    // W slice: w[j] = (W[32kk+j][2r], W[32kk+j][2r+1]) — contiguous float2.
    float w0[32], w1[32];
    #pragma unroll
    for (int j = 0; j < 32; ++j) {
        const float2 wv = ((const float2*)W_res)[(32 * kk + j) * 128 + r];
        w0[j] = wv.x;
        w1[j] = wv.y;
    }
    // Pin in VGPRs: opaque defs the compiler can't sink/rematerialize.
    #pragma unroll
    for (int j = 0; j < 32; ++j) {
        asm volatile("" : "+v"(w0[j]), "+v"(w1[j]));
    }

    float win[CIN];
    if (tid < RES) {
        #pragma unroll
        for (int c = 0; c < CIN; ++c) win[c] = W_in[c * RES + tid];
    }

    if (tid < RES) h[0][tid] = 0.0f;
    __syncthreads();

    const float* xb = x + (size_t)b * SEQ_T * CIN;
    float*       ob = out + (size_t)b * SEQ_T * RES;

    int p = 0;
    for (int t = 0; t < SEQ_T; ++t) {
        // Phase 1: lane-local copy of h chunk, broadcast via readlane.
        float hv = h[p][32 * kk + (tid & 31)];
        float a0 = 0.0f, a1 = 0.0f;
        #pragma unroll
        for (int j = 0; j < 32; ++j) {
            const float hj = __int_as_float(
                __builtin_amdgcn_readlane(__float_as_int(hv), j));
            a0 = fmaf(hj, w0[j], a0);
            a1 = fmaf(hj, w1[j], a1);
        }
        ((float2*)&part[kk][0])[r] = make_float2(a0, a1);

        // Uniform x load for the reducing threads (scalarizes to s_load).
        float xv[CIN];
        if (tid < RES) {
            #pragma unroll
            for (int c = 0; c < CIN; ++c) xv[c] = xb[t * CIN + c];
        }
        __syncthreads();

        // Phase 2: reduce + input projection + tanh + state/output write.
        if (tid < RES) {
            float s = 0.0f;
            #pragma unroll
            for (int c = 0; c < CIN; ++c) s = fmaf(xv[c], win[c], s);
            #pragma unroll
            for (int q = 0; q < 8; ++q) s += part[q][tid];
            float e  = __expf(2.0f * s);
            float hn = 1.0f - 2.0f * __builtin_amdgcn_rcpf(e + 1.0f);
            h[1 - p][tid]     = hn;
            ob[t * RES + tid] = hn;
        }
        __syncthreads();
        p ^= 1;
    }
}

extern "C" void kernel_launch(void* const* d_in, const int* in_sizes, int n_in,
                              void* d_out, int out_size, void* d_ws, size_t ws_size,
                              hipStream_t stream) {
    const float* x     = (const float*)d_in[0];
    const float* W_in  = (const float*)d_in[1];
    const float* W_res = (const float*)d_in[2];
    float*       out   = (float*)d_out;

    esn_scan_kernel<<<BATCH, 1024, 0, stream>>>(x, W_in, W_res, out);
}